// Round 10
// baseline (627.055 us; speedup 1.0000x reference)
//
#include <hip/hip_runtime.h>
#include <hip/hip_bf16.h>
#include <math.h>

#define KK_TOP 1365   // int(2048/3*2)
#define NB 256u       // grid size; == CU count, residency guaranteed

typedef __attribute__((ext_vector_type(8))) short v8s;
typedef __attribute__((ext_vector_type(4))) float f32x4;

#define MFMA16(a, b, c) __builtin_amdgcn_mfma_f32_16x16x32_bf16(a, b, c, 0, 0, 0)

__device__ inline float wave_max_f(float v) {
    #pragma unroll
    for (int m = 1; m < 64; m <<= 1) v = fmaxf(v, __shfl_xor(v, m));
    return v;
}
__device__ inline float wave_min_f(float v) {
    #pragma unroll
    for (int m = 1; m < 64; m <<= 1) v = fminf(v, __shfl_xor(v, m));
    return v;
}
__device__ inline float wave_sum_f(float v) {
    #pragma unroll
    for (int m = 1; m < 64; m <<= 1) v += __shfl_xor(v, m);
    return v;
}
__device__ inline unsigned short bf16bits(float x) {
    __hip_bfloat16 h = __float2bfloat16(x);
    return *reinterpret_cast<unsigned short*>(&h);
}

// Device-scope grid barrier (persistent-kernel pattern). All 256 blocks are
// co-resident by construction (grid == CU count; LDS 65KB -> >=1 block/CU,
// VGPR capped 256 -> one 8-wave block always fits). __threadfence on every
// exit path = release/acquire + per-CU L1 invalidate (G16 stale-line fix).
__device__ __forceinline__ void gsync(unsigned* cnt, unsigned* gen) {
    __syncthreads();
    if (threadIdx.x == 0) {
        unsigned g = atomicAdd(gen, 0u);      // atomic read of generation
        __threadfence();                       // release my writes
        unsigned old = atomicAdd(cnt, 1u);
        if (old == NB - 1u) {
            atomicExch(cnt, 0u);
            __threadfence();
            atomicAdd(gen, 1u);                // wake everyone
        } else {
            while (atomicAdd(gen, 0u) == g) __builtin_amdgcn_s_sleep(2);
        }
        __threadfence();                       // acquire + L1 invalidate
    }
    __syncthreads();
}

// ---------------------------------------------------------------------------
// QKV GEMM tiles, wave-linear over 2048 waves. 256 row-tiles x 24 col-frags.
// ---------------------------------------------------------------------------
template <bool FROMF32>
__device__ __forceinline__ void qkv_tiles(
    const float* Xf, const short* Xbq, const short* Wb,
    short* Qo, short* Ko, short* Vto, int wgid, int g, int c)
{
    for (int t = wgid; t < 6144; t += 2048) {
        const int rt = t / 24, cf = t - rt * 24;
        const int m0 = rt * 16, n0 = cf * 16;
        v8s af[4];
        if (FROMF32) {
            #pragma unroll
            for (int kk = 0; kk < 4; ++kk) {
                const float* xp = Xf + (size_t)(m0 + c) * 128 + kk * 32 + g * 8;
                union { short s[8]; v8s v; } u;
                #pragma unroll
                for (int j = 0; j < 8; ++j) u.s[j] = (short)bf16bits(xp[j]);
                af[kk] = u.v;
            }
        } else {
            #pragma unroll
            for (int kk = 0; kk < 4; ++kk)
                af[kk] = *(const v8s*)(Xbq + (size_t)(m0 + c) * 128 + kk * 32 + g * 8);
        }
        f32x4 acc = {0.f, 0.f, 0.f, 0.f};
        #pragma unroll
        for (int kk = 0; kk < 4; ++kk) {
            v8s bfr = *(const v8s*)(Wb + (size_t)(n0 + c) * 128 + kk * 32 + g * 8);
            acc = MFMA16(af[kk], bfr, acc);
        }
        const int ccol = n0 + c;
        #pragma unroll
        for (int r = 0; r < 4; ++r) {
            const int m = m0 + 4 * g + r;
            const int b = m >> 11, n = m & 2047;
            unsigned short hv = bf16bits(acc[r]);
            if (ccol < 128) {
                int hh = ccol >> 5, d = ccol & 31;
                Qo[((size_t)(b * 4 + hh) * 2048 + n) * 32 + d] = (short)hv;
            } else if (ccol < 256) {
                int c2 = ccol - 128; int hh = c2 >> 5, d = c2 & 31;
                Ko[((size_t)(b * 4 + hh) * 2048 + n) * 32 + d] = (short)hv;
            } else {
                int c2 = ccol - 256; int hh = c2 >> 5, d = c2 & 31;
                Vto[((size_t)(b * 4 + hh) * 32 + d) * 2048 + n] = (short)hv;
            }
        }
    }
}

// PROJ GEMM tiles: 2048 tiles over 2048 waves (1 each).
template <bool EMITB>
__device__ __forceinline__ void proj_tiles(
    const short* Xbq, const short* Wb, const float* bias, const float* resid,
    float* Fo, short* Bo, int wgid, int g, int c)
{
    const int t = wgid;
    const int rt = t >> 3, cf = t & 7;
    const int m0 = rt * 16, n0 = cf * 16;
    v8s af[4];
    #pragma unroll
    for (int kk = 0; kk < 4; ++kk)
        af[kk] = *(const v8s*)(Xbq + (size_t)(m0 + c) * 128 + kk * 32 + g * 8);
    f32x4 acc = {0.f, 0.f, 0.f, 0.f};
    #pragma unroll
    for (int kk = 0; kk < 4; ++kk) {
        v8s bfr = *(const v8s*)(Wb + (size_t)(n0 + c) * 128 + kk * 32 + g * 8);
        acc = MFMA16(af[kk], bfr, acc);
    }
    const int ccol = n0 + c;
    #pragma unroll
    for (int r = 0; r < 4; ++r) {
        const int m = m0 + 4 * g + r;
        float v = acc[r] + bias[ccol] + resid[(size_t)m * 128 + ccol];
        Fo[(size_t)m * 128 + ccol] = v;
        if (EMITB) Bo[(size_t)m * 128 + ccol] = (short)bf16bits(v);
    }
}

// Attention for one virtual block (round-9 attn_mfma_k body, verbatim math).
__device__ __forceinline__ void attn_vblock(
    const short* Qb, const short* Kb, const short* Vt, const unsigned* Ab2,
    short* Ob, float* OLDSf, float* lredf,
    int vb, int tid, int w, int lane, int g, int c)
{
    const int b = vb >> 9, h = (vb >> 7) & 3, r0w = (vb & 127) << 4;
    const int bh = b * 4 + h;
    const int bb = 4 * g;
    __syncthreads();

    const v8s qf = *(const v8s*)(Qb + ((size_t)bh * 2048 + r0w + c) * 32 + g * 8);
    const short* Kp = Kb + (size_t)bh * 2048 * 32;
    const short* Vp = Vt + (size_t)bh * 32 * 2048;
    const unsigned* Mrow = Ab2 + (size_t)(r0w + c) * 64;

    f32x4 o0 = {0.f, 0.f, 0.f, 0.f}, o1 = {0.f, 0.f, 0.f, 0.f};
    float lsum = 0.f;
    const float SC2 = 0.25503487f;   // 32^-0.5 * log2(e)
    const bool lo = (g < 2);
    const int aA = (32 * (g & 1) + c) * 4;
    const int aB = aA + 64;

    #pragma unroll 2
    for (int tt = 0; tt < 8; ++tt) {
        const int kt = tt * 8 + w;
        const int key0 = kt * 32;
        v8s kf0 = *(const v8s*)(Kp + (size_t)(key0 + c) * 32 + g * 8);
        v8s kf1 = *(const v8s*)(Kp + (size_t)(key0 + 16 + c) * 32 + g * 8);
        unsigned mw = Mrow[kt];
        const f32x4 z = {0.f, 0.f, 0.f, 0.f};
        f32x4 s0 = MFMA16(kf0, qf, z);
        f32x4 s1 = MFMA16(kf1, qf, z);

        float p0[4], p1[4];
        #pragma unroll
        for (int r = 0; r < 4; ++r) {
            p0[r] = ((mw >> (bb + r)) & 1u)      ? exp2f(s0[r] * SC2) : 0.f;
            p1[r] = ((mw >> (16 + bb + r)) & 1u) ? exp2f(s1[r] * SC2) : 0.f;
        }
        lsum += p0[0] + p0[1] + p0[2] + p0[3] + p1[0] + p1[1] + p1[2] + p1[3];

        int w00 = (int)bf16bits(p0[0]) | ((int)bf16bits(p0[1]) << 16);
        int w01 = (int)bf16bits(p0[2]) | ((int)bf16bits(p0[3]) << 16);
        int w10 = (int)bf16bits(p1[0]) | ((int)bf16bits(p1[1]) << 16);
        int w11 = (int)bf16bits(p1[2]) | ((int)bf16bits(p1[3]) << 16);

        int e0, e1;
        union { int wv[4]; v8s v; } pf;
        e0 = __builtin_amdgcn_ds_bpermute(aA, w00);
        e1 = __builtin_amdgcn_ds_bpermute(aA, w10);
        pf.wv[0] = lo ? e0 : e1;
        e0 = __builtin_amdgcn_ds_bpermute(aA, w01);
        e1 = __builtin_amdgcn_ds_bpermute(aA, w11);
        pf.wv[1] = lo ? e0 : e1;
        e0 = __builtin_amdgcn_ds_bpermute(aB, w00);
        e1 = __builtin_amdgcn_ds_bpermute(aB, w10);
        pf.wv[2] = lo ? e0 : e1;
        e0 = __builtin_amdgcn_ds_bpermute(aB, w01);
        e1 = __builtin_amdgcn_ds_bpermute(aB, w11);
        pf.wv[3] = lo ? e0 : e1;

        v8s vf0 = *(const v8s*)(Vp + (size_t)c * 2048 + key0 + g * 8);
        v8s vf1 = *(const v8s*)(Vp + (size_t)(16 + c) * 2048 + key0 + g * 8);
        o0 = MFMA16(pf.v, vf0, o0);
        o1 = MFMA16(pf.v, vf1, o1);
    }

    lsum += __shfl_xor(lsum, 16);
    lsum += __shfl_xor(lsum, 32);

    *(f32x4*)&OLDSf[(w * 64 + lane) * 8 + 0] = o0;
    *(f32x4*)&OLDSf[(w * 64 + lane) * 8 + 4] = o1;
    if (lane < 16) lredf[w * 16 + lane] = lsum;
    __syncthreads();

    if (tid < 64) {
        float iv[4];
        #pragma unroll
        for (int r = 0; r < 4; ++r) {
            float s = lredf[bb + r];
            #pragma unroll
            for (int ww = 1; ww < 8; ++ww) s += lredf[ww * 16 + bb + r];
            iv[r] = 1.f / s;
        }
        f32x4 a0 = *(f32x4*)&OLDSf[lane * 8 + 0];
        f32x4 a1 = *(f32x4*)&OLDSf[lane * 8 + 4];
        #pragma unroll
        for (int ww = 1; ww < 8; ++ww) {
            a0 += *(f32x4*)&OLDSf[(ww * 64 + lane) * 8 + 0];
            a1 += *(f32x4*)&OLDSf[(ww * 64 + lane) * 8 + 4];
        }
        #pragma unroll
        for (int r = 0; r < 4; ++r) {
            size_t base = ((size_t)b * 2048 + r0w + bb + r) * 128 + h * 32;
            Ob[base + c]      = (short)bf16bits(a0[r] * iv[r]);
            Ob[base + 16 + c] = (short)bf16bits(a1[r] * iv[r]);
        }
    }
}

// ---------------------------------------------------------------------------
// Persistent mega-kernel: all 9 phases with manual grid barriers.
// 256 blocks x 512 threads, LDS 65 KB, VGPR <= 256.
// ---------------------------------------------------------------------------
__global__ __launch_bounds__(512, 2) void mega_k(
    const float* __restrict__ x, const int* __restrict__ A,
    const float* __restrict__ q_w1, const float* __restrict__ kv_w1,
    const float* __restrict__ proj_w1, const float* __restrict__ proj_b1,
    const float* __restrict__ q_w2, const float* __restrict__ kv_w2,
    const float* __restrict__ proj_w2, const float* __restrict__ proj_b2,
    const float* __restrict__ cq_w, const float* __restrict__ cq_b,
    const float* __restrict__ ck_w, const float* __restrict__ ck_b,
    const float* __restrict__ cv_w, const float* __restrict__ cv_b,
    const float* __restrict__ gc_w, const float* __restrict__ gc_b,
    short* Qb, short* Kb, short* Vt, unsigned* Ab2, short* Ob,
    float* X1, short* X1b, float* X2,
    float* QgT, float* Kg, __hip_bfloat16* SUPt, float* MT, float* B2,
    short* WALLb, unsigned* bar, float* OUT)
{
    __shared__ __align__(16) char smem_[66560];   // 65 KB
    unsigned* cnt = bar;
    unsigned* gen = bar + 16;

    const int bx = blockIdx.x;     // 0..255
    const int tid = threadIdx.x;   // 0..511
    const int w = tid >> 6, lane = tid & 63;
    const int g = lane >> 4, c = lane & 15;
    const int wgid = bx * 8 + w;   // 0..2047

    // ================= P0: prep ==========================================
    {
        const int row = bx * 8 + w;              // 0..2047
        const int* rp = A + (size_t)row * 2048;
        for (int i = 0; i < 32; ++i) {
            unsigned long long bal = __ballot(rp[i * 64 + lane] > 0);
            if (lane == 0)  Ab2[(size_t)row * 64 + 2 * i]     = (unsigned)bal;
            if (lane == 32) Ab2[(size_t)row * 64 + 2 * i + 1] = (unsigned)(bal >> 32);
        }
    }
    if (bx < 32) {
        const int cc = bx * 4 + (tid >> 7);      // 0..127
        const int k = tid & 127;
        float a = 0.f;
        #pragma unroll 4
        for (int i = 0; i < 128; ++i)
            a += cv_w[(size_t)i * 128 + k] * gc_w[(size_t)i * 128 + cc];
        MT[(size_t)cc * 128 + k] = a;
    }
    if (bx == 32 && tid < 128) {
        float s = 0.f;
        #pragma unroll 4
        for (int i = 0; i < 128; ++i)
            s += cv_b[i] * gc_w[(size_t)i * 128 + tid];
        B2[tid] = s;
    }
    if (bx >= 64 && bx < 80) {
        const int base = (bx - 64) * 8192;
        const float* src; int off;
        if (base < 16384)       { src = q_w1;    off = base; }
        else if (base < 49152)  { src = kv_w1;   off = base - 16384; }
        else if (base < 65536)  { src = proj_w1; off = base - 49152; }
        else if (base < 81920)  { src = q_w2;    off = base - 65536; }
        else if (base < 114688) { src = kv_w2;   off = base - 81920; }
        else                    { src = proj_w2; off = base - 114688; }
        short* dst = WALLb + base;
        #pragma unroll 8
        for (int i = 0; i < 16; ++i) {
            int e = tid + i * 512;
            dst[e] = (short)bf16bits(src[off + e]);
        }
    }
    gsync(cnt, gen);

    // ================= P1: QKV-1 =========================================
    qkv_tiles<true>(x, nullptr, WALLb, Qb, Kb, Vt, wgid, g, c);
    gsync(cnt, gen);

    // ================= P2: attention 1 (4 virtual blocks) ================
    {
        float* OLDSf = (float*)smem_;
        float* lredf = (float*)(smem_ + 16384);
        for (int vi = 0; vi < 4; ++vi)
            attn_vblock(Qb, Kb, Vt, Ab2, Ob, OLDSf, lredf,
                        bx * 4 + vi, tid, w, lane, g, c);
    }
    gsync(cnt, gen);

    // ================= P3: PROJ-1 (emit bf16 too) ========================
    proj_tiles<true>(Ob, WALLb + 49152, proj_b1, x, X1, X1b, wgid, g, c);
    gsync(cnt, gen);

    // ================= P4: QKV-2 =========================================
    qkv_tiles<false>(nullptr, X1b, WALLb + 65536, Qb, Kb, Vt, wgid, g, c);
    gsync(cnt, gen);

    // ================= P5: attention 2 ===================================
    {
        float* OLDSf = (float*)smem_;
        float* lredf = (float*)(smem_ + 16384);
        for (int vi = 0; vi < 4; ++vi)
            attn_vblock(Qb, Kb, Vt, Ab2, Ob, OLDSf, lredf,
                        bx * 4 + vi, tid, w, lane, g, c);
    }
    gsync(cnt, gen);

    // ================= P6: PROJ-2 -> X2 ==================================
    proj_tiles<false>(Ob, WALLb + 114688, proj_b2, X1, X2, nullptr, wgid, g, c);
    gsync(cnt, gen);

    // ================= P7: graphmm (frozen f32 numerics) =================
    for (int vb = bx; vb < 384; vb += 256) {
        float (*Xs)[132] = (float(*)[132])smem_;
        float (*Ws)[132] = (float(*)[132])(smem_ + 33792);
        const bool act = (tid < 256);
        const int m0 = (vb & 63) * 64;
        const int y = vb >> 6;
        const float* W0   = (y == 0) ? cq_w : (y == 1) ? ck_w : MT;
        const float* bias = (y == 0) ? cq_b : (y == 1) ? ck_b : B2;
        const int n0 = (y < 2) ? 0 : (y - 2) * 32;

        __syncthreads();
        if (act) {
            #pragma unroll
            for (int i = 0; i < 32; ++i) {
                int idx = tid + i * 256;
                int row = idx >> 7, col = idx & 127;
                Xs[row][col] = X2[(size_t)(m0 + row) * 128 + col];
            }
            #pragma unroll
            for (int i = 0; i < 16; ++i) {
                int idx = tid + i * 256;
                int r = idx >> 7, col = idx & 127;
                Ws[r][col] = W0[(size_t)(n0 + r) * 128 + col];
            }
        }
        __syncthreads();

        if (act) {
            const int r = tid >> 4;
            const int cc = tid & 15;
            float acc[4][2] = {{0.f, 0.f}, {0.f, 0.f}, {0.f, 0.f}, {0.f, 0.f}};

            #pragma unroll
            for (int k = 0; k < 128; k += 4) {
                float4 w0 = *(const float4*)&Ws[cc][k];
                float4 w1 = *(const float4*)&Ws[cc + 16][k];
                #pragma unroll
                for (int i = 0; i < 4; ++i) {
                    float4 xv = *(const float4*)&Xs[r + 16 * i][k];
                    acc[i][0] += xv.x * w0.x + xv.y * w0.y + xv.z * w0.z + xv.w * w0.w;
                    acc[i][1] += xv.x * w1.x + xv.y * w1.y + xv.z * w1.z + xv.w * w1.w;
                }
            }

            #pragma unroll
            for (int i = 0; i < 4; ++i) {
                int m = m0 + r + 16 * i;
                int b = m >> 11, n = m & 2047;
                #pragma unroll
                for (int jj = 0; jj < 2; ++jj) {
                    int ccol = n0 + cc + 16 * jj;
                    float v = acc[i][jj];
                    if (y == 0) {
                        QgT[((size_t)b * 32 + ccol) * 2048 + n] = v + bias[ccol];
                    } else if (y == 1) {
                        Kg[(size_t)m * 32 + ccol] = v + bias[ccol];
                    } else {
                        SUPt[((size_t)b * 128 + ccol) * 2048 + n] = __float2bfloat16(v + bias[ccol]);
                    }
                }
            }
        }
    }
    gsync(cnt, gen);

    // ================= P8: gadjtopk + fused outgemm (2 virtual blocks) ====
    for (int vb = bx; vb < 512; vb += 256) {
        float (*scores)[2048] = (float(*)[2048])smem_;   // 64 KB
        float (*kg_s)[32] = (float(*)[32])(smem_ + 65536);
        const int b = vb >> 8;
        const int r0 = (vb & 255) << 3;

        __syncthreads();
        if (tid < 256) {
            int rr = tid >> 5, d = tid & 31;
            kg_s[rr][d] = Kg[((size_t)b * 2048 + r0 + rr) * 32 + d];
        }
        __syncthreads();

        // phase 1: logits GEMM (frozen fmaf chains)
        const float* Qp = QgT + (size_t)b * 32 * 2048;
        {
            float acc[8][4];
            #pragma unroll
            for (int rr = 0; rr < 8; ++rr)
                #pragma unroll
                for (int s = 0; s < 4; ++s) acc[rr][s] = 0.f;

            for (int dd = 0; dd < 32; ++dd) {
                float qv[8];
                #pragma unroll
                for (int rr = 0; rr < 8; ++rr) qv[rr] = kg_s[rr][dd];
                const float* kp = Qp + (size_t)dd * 2048 + tid;
                #pragma unroll
                for (int s = 0; s < 4; ++s) {
                    float kv = kp[s * 512];
                    #pragma unroll
                    for (int rr = 0; rr < 8; ++rr)
                        acc[rr][s] = fmaf(qv[rr], kv, acc[rr][s]);
                }
            }
            #pragma unroll
            for (int s = 0; s < 4; ++s) {
                int jj = tid + 512 * s;
                #pragma unroll
                for (int rr = 0; rr < 8; ++rr) scores[rr][jj] = acc[rr][s];
            }
        }
        __syncthreads();

        // phases 2-3: wave w owns row r0 + w (frozen numerics)
        float mx = -3.0e38f;
        #pragma unroll
        for (int i = 0; i < 32; ++i) mx = fmaxf(mx, scores[w][lane + i * 64]);
        mx = wave_max_f(mx);

        float sm0 = 0.f;
        #pragma unroll
        for (int i = 0; i < 32; ++i) {
            float p = expf(scores[w][lane + i * 64] - mx);
            scores[w][lane + i * 64] = p;
            sm0 += p;
        }
        sm0 = wave_sum_f(sm0);
        const float ivw = 1.f / sm0;

        unsigned k_[32];
        float mxp = 0.f, mnp = 3.0e38f;
        #pragma unroll
        for (int i = 0; i < 32; ++i) {
            float p = scores[w][lane + i * 64] * ivw;
            k_[i] = __float_as_uint(p);
            mxp = fmaxf(mxp, p);
            mnp = fminf(mnp, p);
        }
        mxp = wave_max_f(mxp);
        mnp = wave_min_f(mnp);
        __syncthreads();   // scores consumed; LDS reusable as ADJ tile

        unsigned thr = __float_as_uint(mnp);
        const unsigned umax = __float_as_uint(mxp);
        const unsigned diff = thr ^ umax;
        if (diff != 0u) {
            const int hb = 31 - __builtin_clz(diff);
            thr = (umax >> (hb + 1)) << (hb + 1);
            for (int bit = hb; bit >= 0; --bit) {
                unsigned cand = thr | (1u << bit);
                int cntk = 0;
                #pragma unroll
                for (int i = 0; i < 32; ++i)
                    cntk += (int)__popcll(__ballot(k_[i] >= cand));
                if (cntk == KK_TOP) { thr = cand; break; }
                if (cntk > KK_TOP) thr = cand;
            }
        }

        int gt_c = 0;
        #pragma unroll
        for (int i = 0; i < 32; ++i)
            gt_c += (int)__popcll(__ballot(k_[i] > thr));
        const int need = KK_TOP - gt_c;

        unsigned keepmask = 0u;
        int running = 0;
        const unsigned long long ltmask = (lane == 0) ? 0ull : (~0ull >> (64 - lane));
        #pragma unroll
        for (int i = 0; i < 32; ++i) {
            bool tie = (k_[i] == thr);
            unsigned long long bal = __ballot(tie);
            int before = running + (int)__popcll(bal & ltmask);
            bool keep = (k_[i] > thr) || (tie && before < need);
            running += (int)__popcll(bal);
            if (keep) keepmask |= (1u << i);
        }

        const float LOG2E = 1.4426950408889634f;
        float sm = 0.f;
        #pragma unroll
        for (int i = 0; i < 32; ++i)
            if ((keepmask >> i) & 1u)
                sm += exp2f((__uint_as_float(k_[i]) - mxp) * LOG2E);
        sm = wave_sum_f(sm);
        const float ivs = 1.f / sm;

        // ADJ row -> swizzled LDS tile
        unsigned short* adjl = (unsigned short*)&scores[0][0];   // [8][2048] bf16
        const int wsw = (w & 7) << 3;
        #pragma unroll
        for (int i = 0; i < 32; ++i) {
            float o = ((keepmask >> i) & 1u)
                        ? exp2f((__uint_as_float(k_[i]) - mxp) * LOG2E) * ivs : 0.f;
            adjl[w * 2048 + ((lane + i * 64) ^ wsw)] = bf16bits(o);
        }
        __syncthreads();

        // fused outgemm: OUT[r0..r0+7][cols w*16..] = ADJ @ SUPt^T
        const short* adjs = (const short*)adjl;
        const short* Bp = (const short*)SUPt + (size_t)b * 128 * 2048;
        const int csw = (c & 7) << 3;
        f32x4 oa = {0.f, 0.f, 0.f, 0.f};
        const v8s zero8 = {0, 0, 0, 0, 0, 0, 0, 0};
        #pragma unroll 2
        for (int kf = 0; kf < 64; ++kf) {
            const int k0 = kf * 32;
            v8s af2 = (c < 8) ? *(const v8s*)(adjs + (c * 2048 + ((k0 + g * 8) ^ csw)))
                              : zero8;
            v8s bf2 = *(const v8s*)(Bp + (size_t)(w * 16 + c) * 2048 + k0 + g * 8);
            oa = MFMA16(af2, bf2, oa);
        }
        if (g < 2) {
            const int col = w * 16 + c;
            const float bias = gc_b[col];
            #pragma unroll
            for (int r = 0; r < 4; ++r)
                OUT[((size_t)b * 2048 + r0 + 4 * g + r) * 128 + col] = oa[r] + bias;
        }
        __syncthreads();   // protect LDS reuse by next virtual block
    }
}

// ---------------------------------------------------------------------------
extern "C" void kernel_launch(void* const* d_in, const int* in_sizes, int n_in,
                              void* d_out, int out_size, void* d_ws, size_t ws_size,
                              hipStream_t stream)
{
    const float* x       = (const float*)d_in[0];
    const int*   A       = (const int*)d_in[1];
    const float* q_w1    = (const float*)d_in[2];
    const float* kv_w1   = (const float*)d_in[3];
    const float* proj_w1 = (const float*)d_in[4];
    const float* proj_b1 = (const float*)d_in[5];
    const float* q_w2    = (const float*)d_in[6];
    const float* kv_w2   = (const float*)d_in[7];
    const float* proj_w2 = (const float*)d_in[8];
    const float* proj_b2 = (const float*)d_in[9];
    const float* cq_w    = (const float*)d_in[10];
    const float* cq_b    = (const float*)d_in[11];
    const float* ck_w    = (const float*)d_in[12];
    const float* ck_b    = (const float*)d_in[13];
    const float* cv_w    = (const float*)d_in[14];
    const float* cv_b    = (const float*)d_in[15];
    const float* gc_w    = (const float*)d_in[16];
    const float* gc_b    = (const float*)d_in[17];
    float* out = (float*)d_out;

    // Workspace carve (bytes, 256-aligned).
    char* wsb = (char*)d_ws;
    short*          Qb   = (short*)         (wsb + 0);          // 1 MB
    short*          Kb   = (short*)         (wsb + 1048576);    // 1 MB
    short*          Vt   = (short*)         (wsb + 2097152);    // 1 MB
    unsigned*       Ab2  = (unsigned*)      (wsb + 3145728);    // 512 KB
    short*          Ob   = (short*)         (wsb + 3670016);    // 1 MB
    float*          X1   = (float*)         (wsb + 4718592);    // 2 MB
    short*          X1b  = (short*)         (wsb + 6815744);    // 1 MB
    float*          X2   = (float*)         (wsb + 7864320);    // 2 MB
    float*          QgT  = (float*)         (wsb + 9961472);    // 512 KB
    float*          Kg   = (float*)         (wsb + 10485760);   // 512 KB
    __hip_bfloat16* SUPt = (__hip_bfloat16*)(wsb + 11010048);   // 1 MB
    float*          MT   = (float*)         (wsb + 12058624);   // 64 KB
    float*          B2   = (float*)         (wsb + 12124160);   // 1 KB
    short*          WALLb= (short*)         (wsb + 12125184);   // 256 KB
    unsigned*       bar  = (unsigned*)      (wsb + 12387328);   // 128 B

    // Barrier state must be zero before the kernel runs (ws is poisoned 0xAA).
    hipMemsetAsync((void*)bar, 0, 128, stream);

    hipLaunchKernelGGL(mega_k, dim3(256), dim3(512), 0, stream,
                       x, A, q_w1, kv_w1, proj_w1, proj_b1,
                       q_w2, kv_w2, proj_w2, proj_b2,
                       cq_w, cq_b, ck_w, ck_b, cv_w, cv_b, gc_w, gc_b,
                       Qb, Kb, Vt, Ab2, Ob, X1, X1b, X2,
                       QgT, Kg, SUPt, MT, B2, WALLb, bar, out);
}